// Round 2
// baseline (2109.902 us; speedup 1.0000x reference)
//
#include <hip/hip_runtime.h>

#define E_EDGES 320000
#define N_NODES 10000
#define F_DIM   128
#define C_DIM   384      // 3*F
#define NRBF_K  20
#define TILE    16       // edges per block-tile
#define TP      20       // padded tile stride (16B-aligned rows, breaks pow2 conflicts)
#define PI_F    3.14159265358979323846f

// ---------------------------------------------------------------- sum(r^2) over all E*3
__global__ void sumsq_kernel(const float* __restrict__ r,
                             float* __restrict__ out) {
    __shared__ float red[4];
    int tid = blockIdx.x * blockDim.x + threadIdx.x;
    int stride = gridDim.x * blockDim.x;
    float acc = 0.f;
    for (int i = tid; i < E_EDGES * 3; i += stride) {
        float x = r[i];
        acc += x * x;
    }
    #pragma unroll
    for (int off = 32; off > 0; off >>= 1)
        acc += __shfl_down(acc, off, 64);
    int lane = threadIdx.x & 63;
    int wave = threadIdx.x >> 6;
    if (lane == 0) red[wave] = acc;
    __syncthreads();
    if (threadIdx.x == 0) {
        float s = red[0] + red[1] + red[2] + red[3];
        atomicAdd(out, s);
    }
}

// ---------------------------------------------------------------- main fused kernel
__global__ __launch_bounds__(384) void main_kernel(
    const float* __restrict__ s,      // E x 128
    const float* __restrict__ r,      // E x 3
    const float* __restrict__ v,      // E x 3 x 128
    const int*   __restrict__ idx_i,  // E
    const float* __restrict__ W_phi,  // 128 x 384
    const float* __restrict__ b_phi,  // 384
    const float* __restrict__ W_w,    // 20 x 384
    const float* __restrict__ b_w,    // 384
    const float* __restrict__ sumsq,  // ws scalar: sum of r^2 (global Frobenius)
    float* __restrict__ out_v,        // N*3*128 (f32, zeroed, atomic accumulate)
    float* __restrict__ out_s)        // N*128
{
    __shared__ float s_tile[F_DIM][TP];         // [k][e]
    __shared__ float rbf_sh[NRBF_K][TP];        // [n][e]
    __shared__ float orn_sh[TILE][3];           // org_rn per edge
    __shared__ float split_sh[C_DIM][TILE + 1]; // [j][e], stride 17
    __shared__ int   idx_sh[TILE];

    const int tid = threadIdx.x;                // 0..383 == output column j
    const int j   = tid;
    const float inv_gn = rsqrtf(*sumsq);        // 1 / ||r||_F (global, matches jnp.linalg.norm(org_r))
    const float bp = b_phi[j];
    const float bw = b_w[j];

    const int ntiles = E_EDGES / TILE;          // 20000 exact
    for (int t = blockIdx.x; t < ntiles; t += gridDim.x) {
        const int e0 = t * TILE;

        // ---- stage: s tile, rbf, org_rn, idx ----
        for (int q = tid; q < TILE * F_DIM; q += 384) {
            int e = q >> 7, k = q & 127;
            s_tile[k][e] = s[(size_t)(e0 + e) * F_DIM + k];
        }
        if (tid < TILE * NRBF_K) {              // 320 threads: one (e,n) each
            int e = tid / NRBF_K, n = tid % NRBF_K;
            float r0 = r[(e0 + e) * 3 + 0];
            float r1 = r[(e0 + e) * 3 + 1];
            float r2 = r[(e0 + e) * 3 + 2];
            float rn = sqrtf(r0 * r0 + r1 * r1 + r2 * r2);
            float arg  = (float)(n + 1) * (PI_F / 5.0f) * rn;
            float tval = sinf(arg) / rn;
            float env  = (tval <= 5.0f) ? 0.5f * (cosf(PI_F * tval / 5.0f) + 1.0f)
                                        : 0.0f;
            rbf_sh[n][e] = env;
        }
        if (tid >= 320 && tid < 320 + TILE * 3) {
            int q = tid - 320; int e = q / 3, d = q % 3;
            orn_sh[e][d] = r[(e0 + e) * 3 + d] * inv_gn;
        }
        if (tid >= 368) {                       // 16 threads
            idx_sh[tid - 368] = idx_i[e0 + (tid - 368)];
        }
        __syncthreads();

        // ---- compute: phi = s@W_phi + b_phi ; w = rbf@W_w + b_w ; split = w*phi ----
        float accp[TILE], accw[TILE];
        #pragma unroll
        for (int e = 0; e < TILE; e++) { accp[e] = bp; accw[e] = bw; }

        for (int k = 0; k < F_DIM; k++) {
            float wv = W_phi[k * C_DIM + j];
            const float4* s4 = (const float4*)(&s_tile[k][0]);
            float sv[TILE];
            *(float4*)&sv[0]  = s4[0];
            *(float4*)&sv[4]  = s4[1];
            *(float4*)&sv[8]  = s4[2];
            *(float4*)&sv[12] = s4[3];
            #pragma unroll
            for (int e = 0; e < TILE; e++) accp[e] += wv * sv[e];
        }
        #pragma unroll
        for (int n = 0; n < NRBF_K; n++) {
            float wv = W_w[n * C_DIM + j];
            const float4* r4 = (const float4*)(&rbf_sh[n][0]);
            float rv[TILE];
            *(float4*)&rv[0]  = r4[0];
            *(float4*)&rv[4]  = r4[1];
            *(float4*)&rv[8]  = r4[2];
            *(float4*)&rv[12] = r4[3];
            #pragma unroll
            for (int e = 0; e < TILE; e++) accw[e] += wv * rv[e];
        }
        #pragma unroll
        for (int e = 0; e < TILE; e++) split_sh[j][e] = accp[e] * accw[e];
        __syncthreads();

        // ---- scatter: out_s += ss ; out_v += sv*v + sr*org_rn ----
        const int f = tid & 127;
        const int d = tid >> 7;                 // wave-uniform (waves 0,1->0; 2,3->1; 4,5->2)
        for (int e = 0; e < TILE; e++) {
            int   idx = idx_sh[e];
            float svv = split_sh[f][e];
            float srr = split_sh[256 + f][e];
            float vv  = v[(size_t)(e0 + e) * C_DIM + tid];
            float msg = svv * vv + srr * orn_sh[e][d];
            atomicAdd(&out_v[((size_t)idx * 3 + d) * F_DIM + f], msg);
            if (d == 0) {
                float ss = split_sh[128 + f][e];
                atomicAdd(&out_s[(size_t)idx * F_DIM + f], ss);
            }
        }
        __syncthreads();
    }
}

extern "C" void kernel_launch(void* const* d_in, const int* in_sizes, int n_in,
                              void* d_out, int out_size, void* d_ws, size_t ws_size,
                              hipStream_t stream) {
    const float* s     = (const float*)d_in[0];
    const float* r     = (const float*)d_in[1];
    const float* v     = (const float*)d_in[2];
    const int*   idx_i = (const int*)d_in[3];
    const float* W_phi = (const float*)d_in[4];
    const float* b_phi = (const float*)d_in[5];
    const float* W_w   = (const float*)d_in[6];
    const float* b_w   = (const float*)d_in[7];

    float* out   = (float*)d_out;               // [out_v (N*3*F)] [out_s (N*F)]
    float* sumsq = (float*)d_ws;                // one scalar (16B zeroed)
    const int NV = N_NODES * 3 * F_DIM;         // 3,840,000

    // d_out / d_ws are poisoned 0xAA before every launch — zero what we accumulate into.
    hipMemsetAsync(d_out, 0, (size_t)out_size * sizeof(float), stream);
    hipMemsetAsync(d_ws, 0, 16, stream);
    sumsq_kernel<<<512, 256, 0, stream>>>(r, sumsq);
    main_kernel<<<1024, 384, 0, stream>>>(s, r, v, idx_i, W_phi, b_phi, W_w, b_w,
                                          sumsq, out, out + NV);
}